// Round 12
// baseline (445.409 us; speedup 1.0000x reference)
//
#include <hip/hip_runtime.h>

typedef __bf16 bf16_t;
typedef __bf16 bf16x4 __attribute__((ext_vector_type(4)));
typedef __bf16 bf16x8 __attribute__((ext_vector_type(8)));
typedef float f32x4 __attribute__((ext_vector_type(4)));
typedef float f32x8 __attribute__((ext_vector_type(8)));

__device__ __forceinline__ void load_lds16(const void* g, void* l) {
    __builtin_amdgcn_global_load_lds((const __attribute__((address_space(1))) void*)g,
                                     (__attribute__((address_space(3))) void*)l, 16, 0, 0);
}

// ---------------- fp32 -> bf16 converts (7 tensors, one launch) ----------------
__global__ void cvt_all_k(const float* __restrict__ q, const float* __restrict__ k,
                          const float* __restrict__ v, const float* __restrict__ wq,
                          const float* __restrict__ wk, const float* __restrict__ wv,
                          const float* __restrict__ wo,
                          bf16_t* __restrict__ oq, bf16_t* __restrict__ ok,
                          bf16_t* __restrict__ ov, bf16_t* __restrict__ owq,
                          bf16_t* __restrict__ owk, bf16_t* __restrict__ owv,
                          bf16_t* __restrict__ owo) {
    int y = blockIdx.y;
    int n = (y < 3) ? 4194304 : 1048576;
    int i = (blockIdx.x * 256 + threadIdx.x) * 4;
    if (i >= n) return;
    const float* s;
    bf16_t* d;
    switch (y) {
        case 0: s = q;  d = oq;  break;
        case 1: s = k;  d = ok;  break;
        case 2: s = v;  d = ov;  break;
        case 3: s = wq; d = owq; break;
        case 4: s = wk; d = owk; break;
        case 5: s = wv; d = owv; break;
        default: s = wo; d = owo; break;
    }
    f32x4 t = *reinterpret_cast<const f32x4*>(s + i);
    *reinterpret_cast<bf16x4*>(d + i) = __builtin_convertvector(t, bf16x4);
}

// ---------------- mask -> bitmask ----------------
__global__ void pack_mask_k(const int* __restrict__ mask, unsigned long long* __restrict__ bits) {
    int e = blockIdx.x * blockDim.x + threadIdx.x;
    unsigned long long b = __ballot(mask[e] != 0);
    if ((threadIdx.x & 63) == 0) bits[e >> 6] = b;
}

// ---------------- Q/K projection GEMM (swapped operands): C = A @ W^T + bias ----
__global__ __launch_bounds__(256, 3) void gemm_qk(
    const bf16_t* __restrict__ qb, const bf16_t* __restrict__ kb,
    const bf16_t* __restrict__ wq, const bf16_t* __restrict__ wk,
    const float* __restrict__ bq, const float* __restrict__ bk,
    bf16_t* __restrict__ Qh, bf16_t* __restrict__ Kh)
{
    const int z = blockIdx.z;
    const bf16_t* A = z ? kb : qb;
    const bf16_t* W = z ? wk : wq;
    const float* bias = z ? bk : bq;
    bf16_t* obf = z ? Kh : Qh;

    __shared__ bf16_t As[128 * 64];
    __shared__ bf16_t Bs[128 * 64];
    const int tid = threadIdx.x;
    const int lane = tid & 63;
    const int wv = tid >> 6;
    const int wr = wv >> 1, wc = wv & 1;
    const int la = lane & 15, lb = lane >> 4;
    const int bRow = blockIdx.x, bCol = blockIdx.y;
    f32x4 acc[4][4] = {};

    for (int k0 = 0; k0 < 1024; k0 += 64) {
        __syncthreads();
        for (int i = 0; i < 4; ++i) {
            int o = i * 4096 + tid * 16;
            int row = o >> 7;
            int cb = (o & 127) ^ ((row & 7) << 4);
            const char* sa = (const char*)A + (((size_t)(bRow * 128 + row)) * 1024 + k0) * 2 + cb;
            load_lds16(sa, (char*)As + i * 4096 + wv * 1024);
            const char* sb = (const char*)W + (((size_t)(bCol * 128 + row)) * 1024 + k0) * 2 + cb;
            load_lds16(sb, (char*)Bs + i * 4096 + wv * 1024);
        }
        __syncthreads();

        bf16x8 af[2][4], bfr[2][4];
        for (int mi = 0; mi < 4; ++mi) {
            int row = wr * 64 + mi * 16 + la;
            const char* base = (const char*)As + row * 128;
            int sw = (row & 7) << 4;
            af[0][mi] = *reinterpret_cast<const bf16x8*>(base + ((lb * 16) ^ sw));
            af[1][mi] = *reinterpret_cast<const bf16x8*>(base + ((64 + lb * 16) ^ sw));
        }
        for (int ni = 0; ni < 4; ++ni) {
            int row = wc * 64 + ni * 16 + la;
            const char* base = (const char*)Bs + row * 128;
            int sw = (row & 7) << 4;
            bfr[0][ni] = *reinterpret_cast<const bf16x8*>(base + ((lb * 16) ^ sw));
            bfr[1][ni] = *reinterpret_cast<const bf16x8*>(base + ((64 + lb * 16) ^ sw));
        }
        for (int kk = 0; kk < 2; ++kk)
            for (int mi = 0; mi < 4; ++mi)
                for (int ni = 0; ni < 4; ++ni)
                    acc[mi][ni] = __builtin_amdgcn_mfma_f32_16x16x32_bf16(
                        bfr[kk][ni], af[kk][mi], acc[mi][ni], 0, 0, 0);
    }

    for (int mi = 0; mi < 4; ++mi) {
        int n = bRow * 128 + wr * 64 + mi * 16 + la;
        int b_ = n >> 11, s_ = n & 2047;
        for (int ni = 0; ni < 4; ++ni) {
            int colo0 = bCol * 128 + wc * 64 + ni * 16 + lb * 4;
            f32x4 bv4 = *reinterpret_cast<const f32x4*>(&bias[colo0]);
            f32x4 vv = acc[mi][ni] + bv4;
            int h = colo0 >> 6, d0 = colo0 & 63;
            bf16x4 v4 = __builtin_convertvector(vv, bf16x4);
            *reinterpret_cast<bf16x4*>(
                &obf[(((size_t)(b_ * 16 + h) * 2048 + s_) << 6) + d0]) = v4;
        }
    }
}

// ---------------- V projection GEMM: V -> (b,h,dh,s) transposed ----------------
__global__ __launch_bounds__(256, 3) void gemm_v(
    const bf16_t* __restrict__ vb, const bf16_t* __restrict__ wv_,
    const float* __restrict__ bv, bf16_t* __restrict__ Vt)
{
    __shared__ bf16_t As[128 * 64];
    __shared__ bf16_t Bs[128 * 64];
    const int tid = threadIdx.x;
    const int lane = tid & 63;
    const int wv = tid >> 6;
    const int wr = wv >> 1, wc = wv & 1;
    const int la = lane & 15, lb = lane >> 4;
    const int bRow = blockIdx.x, bCol = blockIdx.y;
    f32x4 acc[4][4] = {};

    for (int k0 = 0; k0 < 1024; k0 += 64) {
        __syncthreads();
        for (int i = 0; i < 4; ++i) {
            int o = i * 4096 + tid * 16;
            int row = o >> 7;
            int cb = (o & 127) ^ ((row & 7) << 4);
            const char* sa = (const char*)vb + (((size_t)(bRow * 128 + row)) * 1024 + k0) * 2 + cb;
            load_lds16(sa, (char*)As + i * 4096 + wv * 1024);
            const char* sb = (const char*)wv_ + (((size_t)(bCol * 128 + row)) * 1024 + k0) * 2 + cb;
            load_lds16(sb, (char*)Bs + i * 4096 + wv * 1024);
        }
        __syncthreads();

        bf16x8 af[2][4], bfr[2][4];
        for (int mi = 0; mi < 4; ++mi) {
            int row = wr * 64 + mi * 16 + la;
            const char* base = (const char*)As + row * 128;
            int sw = (row & 7) << 4;
            af[0][mi] = *reinterpret_cast<const bf16x8*>(base + ((lb * 16) ^ sw));
            af[1][mi] = *reinterpret_cast<const bf16x8*>(base + ((64 + lb * 16) ^ sw));
        }
        for (int ni = 0; ni < 4; ++ni) {
            int row = wc * 64 + ni * 16 + la;
            const char* base = (const char*)Bs + row * 128;
            int sw = (row & 7) << 4;
            bfr[0][ni] = *reinterpret_cast<const bf16x8*>(base + ((lb * 16) ^ sw));
            bfr[1][ni] = *reinterpret_cast<const bf16x8*>(base + ((64 + lb * 16) ^ sw));
        }
        for (int kk = 0; kk < 2; ++kk)
            for (int mi = 0; mi < 4; ++mi)
                for (int ni = 0; ni < 4; ++ni)
                    acc[mi][ni] = __builtin_amdgcn_mfma_f32_16x16x32_bf16(
                        af[kk][mi], bfr[kk][ni], acc[mi][ni], 0, 0, 0);
    }

    for (int ni = 0; ni < 4; ++ni) {
        int colo = bCol * 128 + wc * 64 + ni * 16 + la;
        float bvv = bv[colo];
        int h = colo >> 6, d = colo & 63;
        for (int mi = 0; mi < 4; ++mi) {
            int n0 = bRow * 128 + wr * 64 + mi * 16 + lb * 4;
            int b_ = n0 >> 11, s0 = n0 & 2047;
            f32x4 vv = acc[mi][ni];
            vv[0] += bvv; vv[1] += bvv; vv[2] += bvv; vv[3] += bvv;
            bf16x4 v4 = __builtin_convertvector(vv, bf16x4);
            *reinterpret_cast<bf16x4*>(
                &Vt[((size_t)(b_ * 16 + h) * 64 + d) * 2048 + s0]) = v4;
        }
    }
}

// ---------------- output projection GEMM (swapped): out = attn @ Wo^T + bo ----
__global__ __launch_bounds__(256, 3) void gemm_out(
    const bf16_t* __restrict__ A, const bf16_t* __restrict__ W,
    const float* __restrict__ bias, float* __restrict__ ofp)
{
    __shared__ bf16_t As[128 * 64];
    __shared__ bf16_t Bs[128 * 64];
    const int tid = threadIdx.x;
    const int lane = tid & 63;
    const int wv = tid >> 6;
    const int wr = wv >> 1, wc = wv & 1;
    const int la = lane & 15, lb = lane >> 4;
    const int bRow = blockIdx.x, bCol = blockIdx.y;
    f32x4 acc[4][4] = {};

    for (int k0 = 0; k0 < 1024; k0 += 64) {
        __syncthreads();
        for (int i = 0; i < 4; ++i) {
            int o = i * 4096 + tid * 16;
            int row = o >> 7;
            int cb = (o & 127) ^ ((row & 7) << 4);
            const char* sa = (const char*)A + (((size_t)(bRow * 128 + row)) * 1024 + k0) * 2 + cb;
            load_lds16(sa, (char*)As + i * 4096 + wv * 1024);
            const char* sb = (const char*)W + (((size_t)(bCol * 128 + row)) * 1024 + k0) * 2 + cb;
            load_lds16(sb, (char*)Bs + i * 4096 + wv * 1024);
        }
        __syncthreads();

        bf16x8 af[2][4], bfr[2][4];
        for (int mi = 0; mi < 4; ++mi) {
            int row = wr * 64 + mi * 16 + la;
            const char* base = (const char*)As + row * 128;
            int sw = (row & 7) << 4;
            af[0][mi] = *reinterpret_cast<const bf16x8*>(base + ((lb * 16) ^ sw));
            af[1][mi] = *reinterpret_cast<const bf16x8*>(base + ((64 + lb * 16) ^ sw));
        }
        for (int ni = 0; ni < 4; ++ni) {
            int row = wc * 64 + ni * 16 + la;
            const char* base = (const char*)Bs + row * 128;
            int sw = (row & 7) << 4;
            bfr[0][ni] = *reinterpret_cast<const bf16x8*>(base + ((lb * 16) ^ sw));
            bfr[1][ni] = *reinterpret_cast<const bf16x8*>(base + ((64 + lb * 16) ^ sw));
        }
        for (int kk = 0; kk < 2; ++kk)
            for (int mi = 0; mi < 4; ++mi)
                for (int ni = 0; ni < 4; ++ni)
                    acc[mi][ni] = __builtin_amdgcn_mfma_f32_16x16x32_bf16(
                        bfr[kk][ni], af[kk][mi], acc[mi][ni], 0, 0, 0);
    }

    for (int mi = 0; mi < 4; ++mi) {
        int n = bRow * 128 + wr * 64 + mi * 16 + la;
        for (int ni = 0; ni < 4; ++ni) {
            int colo0 = bCol * 128 + wc * 64 + ni * 16 + lb * 4;
            f32x4 bv4 = *reinterpret_cast<const f32x4*>(&bias[colo0]);
            f32x4 vv = acc[mi][ni] + bv4;
            __builtin_nontemporal_store(
                vv, reinterpret_cast<f32x4*>(&ofp[(size_t)n * 1024 + colo0]));
        }
    }
}

// ---------------- fused scores + softmax + PV ----------------
// grid 1024 (XCD-swizzled); block 256 = 4 waves x 16 q-rows; 16 dbuf'd 128-kv
// chunks. kv-PERMUTED QK tiles: tile (t,h) covers kv t*32 + (la>>2)*8 + h*4 +
// (la&3), so output lane (la,lg) holds P[q=la][kv=t*32+lg*8+h*4+r] — tiles
// h=0,1 give each lane the 8 consecutive kv the PV A-frag needs. P->bf16 is a
// pure in-register convertvector: NO P LDS buffer, no lgkmcnt round-trip.
// LDS row swizzle s=(row&3)|(((row>>3)&1)<<2) gives 8 distinct offsets over
// the permuted 16-row read set (2-way = free). No max-subtraction.
__global__ __launch_bounds__(256, 4) void attn_fused_k(
    const bf16_t* __restrict__ Qh, const bf16_t* __restrict__ Kh,
    const bf16_t* __restrict__ Vt, const unsigned int* __restrict__ mbits,
    float* __restrict__ P, bf16_t* __restrict__ attn)
{
    __shared__ bf16_t Ks[2][128 * 64];  // 2 x 16 KB swizzled K chunks (dbuf)

    // XCD-bijective swizzle: 1024 = 8 XCDs x 128 -> each XCD owns 4 heads
    const int wg = blockIdx.x;
    const int swg = (wg & 7) * 128 + (wg >> 3);
    const int bh = swg >> 5, qs = swg & 31;

    const int tid = threadIdx.x, lane = tid & 63, wv = tid >> 6;  // 4 waves
    const int la = lane & 15, lg = lane >> 4;
    const int b_ = bh >> 4;
    const int qbase = qs * 64 + wv * 16;

    bf16x8 qf0, qf1;
    {
        const bf16_t* qrow = Qh + ((size_t)bh * 2048 + qbase + la) * 64 + lg * 8;
        qf0 = *reinterpret_cast<const bf16x8*>(qrow);
        qf1 = *reinterpret_cast<const bf16x8*>(qrow + 32);
    }
    const char* Khb = (const char*)(Kh + ((size_t)bh << 17));
    const bf16_t* Vtb = Vt + ((size_t)bh << 17);
    const unsigned int* mrow = mbits + ((size_t)b_ * 2048 + qbase + la) * 64;
    const float SC = 0.125f * 1.4426950408889634f;
    // permuted K row for tile (t,h): krow & 3 == la & 3, (krow>>3)&1 == (la>>2)&1
    const int krbase = ((la >> 2) << 3) + (la & 3);
    const int ksw = (((la & 3) | (((la >> 2) & 1) << 2)) << 4);

#define STAGE_K(c, bsel)                                                      \
    for (int i = 0; i < 4; ++i) {                                             \
        int o = i * 4096 + tid * 16;                                          \
        int row = o >> 7;                                                     \
        int cb = (o & 127) ^ ((((row & 3) | (((row >> 3) & 1) << 2))) << 4);  \
        load_lds16(Khb + (size_t)(c) * 16384 + row * 128 + cb,                \
                   (char*)Ks[bsel] + i * 4096 + (tid >> 3) * 128);            \
    }

    // ---- pass 1: row sums of exp2(logit) ----
    float ssum = 0.f;
    uint4 mws = *reinterpret_cast<const uint4*>(mrow);
    STAGE_K(0, 0)
    __syncthreads();
    for (int c = 0; c < 16; ++c) {
        int cn = (c < 15) ? c + 1 : 15;
        uint4 mnext = *reinterpret_cast<const uint4*>(mrow + cn * 4);  // prefetch
        if (c < 15) { STAGE_K(c + 1, (c + 1) & 1) }
        __builtin_amdgcn_sched_barrier(0);
        const char* Kbase = (const char*)Ks[c & 1];
        unsigned mwarr[4] = {mws.x, mws.y, mws.z, mws.w};
        __builtin_amdgcn_s_setprio(1);
#pragma unroll
        for (int t = 0; t < 4; ++t) {
#pragma unroll
            for (int h = 0; h < 2; ++h) {
                int krow = t * 32 + h * 4 + krbase;
                const char* kb = Kbase + krow * 128;
                bf16x8 kf0 = *reinterpret_cast<const bf16x8*>(kb + ((lg * 16) ^ ksw));
                bf16x8 kf1 = *reinterpret_cast<const bf16x8*>(kb + ((64 + lg * 16) ^ ksw));
                f32x4 acc = {};
                acc = __builtin_amdgcn_mfma_f32_16x16x32_bf16(kf0, qf0, acc, 0, 0, 0);
                acc = __builtin_amdgcn_mfma_f32_16x16x32_bf16(kf1, qf1, acc, 0, 0, 0);
                unsigned mw = mwarr[t];
                int sh = lg * 8 + h * 4;
                for (int r = 0; r < 4; ++r) {
                    float tt = __builtin_amdgcn_exp2f(acc[r] * SC);
                    ssum += ((mw >> (sh + r)) & 1u) ? tt : 0.f;
                }
            }
        }
        __builtin_amdgcn_s_setprio(0);
        __syncthreads();
        mws = mnext;
    }
    // reduce over the 4 lg groups (each lane's q-row = la)
    ssum += __shfl_xor(ssum, 16, 64);
    ssum += __shfl_xor(ssum, 32, 64);
    // v_log_f32 IS log2 -> exp2(x*SC - log2(ssum)) = exp2(x*SC)/ssum
    const float nls = -__builtin_amdgcn_logf(ssum);

    // ---- pass 2: recompute, folded-norm exp2, NT P stores, in-reg PV ----
    f32x4 accpv[4] = {};
    float* Pq = P + ((size_t)bh << 22) + (size_t)(qbase + la) * 2048;
    mws = *reinterpret_cast<const uint4*>(mrow);
    STAGE_K(0, 0)
    __syncthreads();
    for (int c = 0; c < 16; ++c) {
        int cn = (c < 15) ? c + 1 : 15;
        uint4 mnext = *reinterpret_cast<const uint4*>(mrow + cn * 4);  // prefetch
        if (c < 15) { STAGE_K(c + 1, (c + 1) & 1) }
        __builtin_amdgcn_sched_barrier(0);
        const char* Kbase = (const char*)Ks[c & 1];
        unsigned mwarr[4] = {mws.x, mws.y, mws.z, mws.w};
        __builtin_amdgcn_s_setprio(1);
#pragma unroll
        for (int t = 0; t < 4; ++t) {
            f32x4 pv2[2];
#pragma unroll
            for (int h = 0; h < 2; ++h) {
                int krow = t * 32 + h * 4 + krbase;
                const char* kb = Kbase + krow * 128;
                bf16x8 kf0 = *reinterpret_cast<const bf16x8*>(kb + ((lg * 16) ^ ksw));
                bf16x8 kf1 = *reinterpret_cast<const bf16x8*>(kb + ((64 + lg * 16) ^ ksw));
                f32x4 acc = {};
                acc = __builtin_amdgcn_mfma_f32_16x16x32_bf16(kf0, qf0, acc, 0, 0, 0);
                acc = __builtin_amdgcn_mfma_f32_16x16x32_bf16(kf1, qf1, acc, 0, 0, 0);
                unsigned mw = mwarr[t];
                int sh = lg * 8 + h * 4;
                f32x4 pv;
                for (int r = 0; r < 4; ++r) {
                    float tt = __builtin_amdgcn_exp2f(__builtin_fmaf(acc[r], SC, nls));
                    pv[r] = ((mw >> (sh + r)) & 1u) ? tt : 0.f;
                }
                pv2[h] = pv;
                __builtin_nontemporal_store(
                    pv, reinterpret_cast<f32x4*>(Pq + c * 128 + t * 32 + lg * 8 + h * 4));
            }
            // PV A-frag: pure in-register — lane holds kv t*32+lg*8+0..7
            f32x8 af8 = {pv2[0][0], pv2[0][1], pv2[0][2], pv2[0][3],
                         pv2[1][0], pv2[1][1], pv2[1][2], pv2[1][3]};
            bf16x8 pa = __builtin_convertvector(af8, bf16x8);
            const bf16_t* vb2 = Vtb + c * 128 + t * 32 + lg * 8;
            for (int ni = 0; ni < 4; ++ni) {
                bf16x8 vf = *reinterpret_cast<const bf16x8*>(vb2 + (size_t)(ni * 16 + la) * 2048);
                accpv[ni] = __builtin_amdgcn_mfma_f32_16x16x32_bf16(pa, vf, accpv[ni], 0, 0, 0);
            }
        }
        __builtin_amdgcn_s_setprio(0);
        // counted wait: mask + 4 stage loads are older than the 8 NT stores
        asm volatile("s_waitcnt vmcnt(8)" ::: "memory");
        __builtin_amdgcn_s_barrier();
        mws = mnext;
    }
#undef STAGE_K

    bf16_t* ab = attn + ((size_t)bh << 17);
    for (int ni = 0; ni < 4; ++ni)
        for (int r = 0; r < 4; ++r)
            ab[(size_t)(qbase + lg * 4 + r) * 64 + ni * 16 + la] = (bf16_t)accpv[ni][r];
}

extern "C" void kernel_launch(void* const* d_in, const int* in_sizes, int n_in,
                              void* d_out, int out_size, void* d_ws, size_t ws_size,
                              hipStream_t stream) {
    const float* q  = (const float*)d_in[0];
    const float* k  = (const float*)d_in[1];
    const float* v  = (const float*)d_in[2];
    const int* mask = (const int*)d_in[3];
    const float* Wq = (const float*)d_in[4];
    const float* bq = (const float*)d_in[5];
    const float* Wk = (const float*)d_in[6];
    const float* bk = (const float*)d_in[7];
    const float* Wv = (const float*)d_in[8];
    const float* bv = (const float*)d_in[9];
    const float* Wo = (const float*)d_in[10];
    const float* bo = (const float*)d_in[11];

    char* ws = (char*)d_ws;
    bf16_t* qb    = (bf16_t*)(ws + 0);
    bf16_t* kb    = (bf16_t*)(ws + 8388608);
    bf16_t* vb    = (bf16_t*)(ws + 16777216);
    bf16_t* wqb   = (bf16_t*)(ws + 25165824);
    bf16_t* wkb   = (bf16_t*)(ws + 27262976);
    bf16_t* wvb   = (bf16_t*)(ws + 29360128);
    bf16_t* wob   = (bf16_t*)(ws + 31457280);
    bf16_t* Qh    = (bf16_t*)(ws + 33554432);
    bf16_t* Kh    = (bf16_t*)(ws + 41943040);
    bf16_t* Vt    = (bf16_t*)(ws + 50331648);
    bf16_t* attnb = (bf16_t*)(ws + 58720256);
    unsigned long long* mbits = (unsigned long long*)(ws + 67108864);

    float* out   = (float*)d_out;
    float* score = out + 4194304;

    cvt_all_k<<<dim3(4096, 7), 256, 0, stream>>>(q, k, v, Wq, Wk, Wv, Wo,
                                                 qb, kb, vb, wqb, wkb, wvb, wob);
    pack_mask_k<<<32768, 256, 0, stream>>>(mask, mbits);

    gemm_qk<<<dim3(32, 8, 2), 256, 0, stream>>>(qb, kb, wqb, wkb, bq, bk, Qh, Kh);
    gemm_v<<<dim3(32, 8), 256, 0, stream>>>(vb, wvb, bv, Vt);

    attn_fused_k<<<1024, 256, 0, stream>>>(Qh, Kh, Vt, (const unsigned int*)mbits,
                                           score, attnb);

    gemm_out<<<dim3(32, 8), 256, 0, stream>>>(attnb, wob, bo, out);
}

// Round 13
// 299.063 us; speedup vs baseline: 1.4893x; 1.4893x over previous
//
#include <hip/hip_runtime.h>

typedef __bf16 bf16_t;
typedef __bf16 bf16x4 __attribute__((ext_vector_type(4)));
typedef __bf16 bf16x8 __attribute__((ext_vector_type(8)));
typedef float f32x4 __attribute__((ext_vector_type(4)));

__device__ __forceinline__ void load_lds16(const void* g, void* l) {
    __builtin_amdgcn_global_load_lds((const __attribute__((address_space(1))) void*)g,
                                     (__attribute__((address_space(3))) void*)l, 16, 0, 0);
}

// ---------------- fp32 -> bf16 converts (7 tensors, one launch) ----------------
__global__ void cvt_all_k(const float* __restrict__ q, const float* __restrict__ k,
                          const float* __restrict__ v, const float* __restrict__ wq,
                          const float* __restrict__ wk, const float* __restrict__ wv,
                          const float* __restrict__ wo,
                          bf16_t* __restrict__ oq, bf16_t* __restrict__ ok,
                          bf16_t* __restrict__ ov, bf16_t* __restrict__ owq,
                          bf16_t* __restrict__ owk, bf16_t* __restrict__ owv,
                          bf16_t* __restrict__ owo) {
    int y = blockIdx.y;
    int n = (y < 3) ? 4194304 : 1048576;
    int i = (blockIdx.x * 256 + threadIdx.x) * 4;
    if (i >= n) return;
    const float* s;
    bf16_t* d;
    switch (y) {
        case 0: s = q;  d = oq;  break;
        case 1: s = k;  d = ok;  break;
        case 2: s = v;  d = ov;  break;
        case 3: s = wq; d = owq; break;
        case 4: s = wk; d = owk; break;
        case 5: s = wv; d = owv; break;
        default: s = wo; d = owo; break;
    }
    f32x4 t = *reinterpret_cast<const f32x4*>(s + i);
    *reinterpret_cast<bf16x4*>(d + i) = __builtin_convertvector(t, bf16x4);
}

// ---------------- mask -> bitmask ----------------
__global__ void pack_mask_k(const int* __restrict__ mask, unsigned long long* __restrict__ bits) {
    int e = blockIdx.x * blockDim.x + threadIdx.x;
    unsigned long long b = __ballot(mask[e] != 0);
    if ((threadIdx.x & 63) == 0) bits[e >> 6] = b;
}

// ---------------- Q/K projection GEMM (swapped operands): C = A @ W^T + bias ----
__global__ __launch_bounds__(256, 3) void gemm_qk(
    const bf16_t* __restrict__ qb, const bf16_t* __restrict__ kb,
    const bf16_t* __restrict__ wq, const bf16_t* __restrict__ wk,
    const float* __restrict__ bq, const float* __restrict__ bk,
    bf16_t* __restrict__ Qh, bf16_t* __restrict__ Kh)
{
    const int z = blockIdx.z;
    const bf16_t* A = z ? kb : qb;
    const bf16_t* W = z ? wk : wq;
    const float* bias = z ? bk : bq;
    bf16_t* obf = z ? Kh : Qh;

    __shared__ bf16_t As[128 * 64];
    __shared__ bf16_t Bs[128 * 64];
    const int tid = threadIdx.x;
    const int lane = tid & 63;
    const int wv = tid >> 6;
    const int wr = wv >> 1, wc = wv & 1;
    const int la = lane & 15, lb = lane >> 4;
    const int bRow = blockIdx.x, bCol = blockIdx.y;
    f32x4 acc[4][4] = {};

    for (int k0 = 0; k0 < 1024; k0 += 64) {
        __syncthreads();
        for (int i = 0; i < 4; ++i) {
            int o = i * 4096 + tid * 16;
            int row = o >> 7;
            int cb = (o & 127) ^ ((row & 7) << 4);
            const char* sa = (const char*)A + (((size_t)(bRow * 128 + row)) * 1024 + k0) * 2 + cb;
            load_lds16(sa, (char*)As + i * 4096 + wv * 1024);
            const char* sb = (const char*)W + (((size_t)(bCol * 128 + row)) * 1024 + k0) * 2 + cb;
            load_lds16(sb, (char*)Bs + i * 4096 + wv * 1024);
        }
        __syncthreads();

        bf16x8 af[2][4], bfr[2][4];
        for (int mi = 0; mi < 4; ++mi) {
            int row = wr * 64 + mi * 16 + la;
            const char* base = (const char*)As + row * 128;
            int sw = (row & 7) << 4;
            af[0][mi] = *reinterpret_cast<const bf16x8*>(base + ((lb * 16) ^ sw));
            af[1][mi] = *reinterpret_cast<const bf16x8*>(base + ((64 + lb * 16) ^ sw));
        }
        for (int ni = 0; ni < 4; ++ni) {
            int row = wc * 64 + ni * 16 + la;
            const char* base = (const char*)Bs + row * 128;
            int sw = (row & 7) << 4;
            bfr[0][ni] = *reinterpret_cast<const bf16x8*>(base + ((lb * 16) ^ sw));
            bfr[1][ni] = *reinterpret_cast<const bf16x8*>(base + ((64 + lb * 16) ^ sw));
        }
        for (int kk = 0; kk < 2; ++kk)
            for (int mi = 0; mi < 4; ++mi)
                for (int ni = 0; ni < 4; ++ni)
                    acc[mi][ni] = __builtin_amdgcn_mfma_f32_16x16x32_bf16(
                        bfr[kk][ni], af[kk][mi], acc[mi][ni], 0, 0, 0);
    }

    for (int mi = 0; mi < 4; ++mi) {
        int n = bRow * 128 + wr * 64 + mi * 16 + la;
        int b_ = n >> 11, s_ = n & 2047;
        for (int ni = 0; ni < 4; ++ni) {
            int colo0 = bCol * 128 + wc * 64 + ni * 16 + lb * 4;
            f32x4 bv4 = *reinterpret_cast<const f32x4*>(&bias[colo0]);
            f32x4 vv = acc[mi][ni] + bv4;
            int h = colo0 >> 6, d0 = colo0 & 63;
            bf16x4 v4 = __builtin_convertvector(vv, bf16x4);
            *reinterpret_cast<bf16x4*>(
                &obf[(((size_t)(b_ * 16 + h) * 2048 + s_) << 6) + d0]) = v4;
        }
    }
}

// ---------------- V projection GEMM: V -> (b,h,dh,s) transposed ----------------
__global__ __launch_bounds__(256, 3) void gemm_v(
    const bf16_t* __restrict__ vb, const bf16_t* __restrict__ wv_,
    const float* __restrict__ bv, bf16_t* __restrict__ Vt)
{
    __shared__ bf16_t As[128 * 64];
    __shared__ bf16_t Bs[128 * 64];
    const int tid = threadIdx.x;
    const int lane = tid & 63;
    const int wv = tid >> 6;
    const int wr = wv >> 1, wc = wv & 1;
    const int la = lane & 15, lb = lane >> 4;
    const int bRow = blockIdx.x, bCol = blockIdx.y;
    f32x4 acc[4][4] = {};

    for (int k0 = 0; k0 < 1024; k0 += 64) {
        __syncthreads();
        for (int i = 0; i < 4; ++i) {
            int o = i * 4096 + tid * 16;
            int row = o >> 7;
            int cb = (o & 127) ^ ((row & 7) << 4);
            const char* sa = (const char*)vb + (((size_t)(bRow * 128 + row)) * 1024 + k0) * 2 + cb;
            load_lds16(sa, (char*)As + i * 4096 + wv * 1024);
            const char* sb = (const char*)wv_ + (((size_t)(bCol * 128 + row)) * 1024 + k0) * 2 + cb;
            load_lds16(sb, (char*)Bs + i * 4096 + wv * 1024);
        }
        __syncthreads();

        bf16x8 af[2][4], bfr[2][4];
        for (int mi = 0; mi < 4; ++mi) {
            int row = wr * 64 + mi * 16 + la;
            const char* base = (const char*)As + row * 128;
            int sw = (row & 7) << 4;
            af[0][mi] = *reinterpret_cast<const bf16x8*>(base + ((lb * 16) ^ sw));
            af[1][mi] = *reinterpret_cast<const bf16x8*>(base + ((64 + lb * 16) ^ sw));
        }
        for (int ni = 0; ni < 4; ++ni) {
            int row = wc * 64 + ni * 16 + la;
            const char* base = (const char*)Bs + row * 128;
            int sw = (row & 7) << 4;
            bfr[0][ni] = *reinterpret_cast<const bf16x8*>(base + ((lb * 16) ^ sw));
            bfr[1][ni] = *reinterpret_cast<const bf16x8*>(base + ((64 + lb * 16) ^ sw));
        }
        for (int kk = 0; kk < 2; ++kk)
            for (int mi = 0; mi < 4; ++mi)
                for (int ni = 0; ni < 4; ++ni)
                    acc[mi][ni] = __builtin_amdgcn_mfma_f32_16x16x32_bf16(
                        af[kk][mi], bfr[kk][ni], acc[mi][ni], 0, 0, 0);
    }

    for (int ni = 0; ni < 4; ++ni) {
        int colo = bCol * 128 + wc * 64 + ni * 16 + la;
        float bvv = bv[colo];
        int h = colo >> 6, d = colo & 63;
        for (int mi = 0; mi < 4; ++mi) {
            int n0 = bRow * 128 + wr * 64 + mi * 16 + lb * 4;
            int b_ = n0 >> 11, s0 = n0 & 2047;
            f32x4 vv = acc[mi][ni];
            vv[0] += bvv; vv[1] += bvv; vv[2] += bvv; vv[3] += bvv;
            bf16x4 v4 = __builtin_convertvector(vv, bf16x4);
            *reinterpret_cast<bf16x4*>(
                &Vt[((size_t)(b_ * 16 + h) * 64 + d) * 2048 + s0]) = v4;
        }
    }
}

// ---------------- output projection GEMM (swapped): out = attn @ Wo^T + bo ----
__global__ __launch_bounds__(256, 3) void gemm_out(
    const bf16_t* __restrict__ A, const bf16_t* __restrict__ W,
    const float* __restrict__ bias, float* __restrict__ ofp)
{
    __shared__ bf16_t As[128 * 64];
    __shared__ bf16_t Bs[128 * 64];
    const int tid = threadIdx.x;
    const int lane = tid & 63;
    const int wv = tid >> 6;
    const int wr = wv >> 1, wc = wv & 1;
    const int la = lane & 15, lb = lane >> 4;
    const int bRow = blockIdx.x, bCol = blockIdx.y;
    f32x4 acc[4][4] = {};

    for (int k0 = 0; k0 < 1024; k0 += 64) {
        __syncthreads();
        for (int i = 0; i < 4; ++i) {
            int o = i * 4096 + tid * 16;
            int row = o >> 7;
            int cb = (o & 127) ^ ((row & 7) << 4);
            const char* sa = (const char*)A + (((size_t)(bRow * 128 + row)) * 1024 + k0) * 2 + cb;
            load_lds16(sa, (char*)As + i * 4096 + wv * 1024);
            const char* sb = (const char*)W + (((size_t)(bCol * 128 + row)) * 1024 + k0) * 2 + cb;
            load_lds16(sb, (char*)Bs + i * 4096 + wv * 1024);
        }
        __syncthreads();

        bf16x8 af[2][4], bfr[2][4];
        for (int mi = 0; mi < 4; ++mi) {
            int row = wr * 64 + mi * 16 + la;
            const char* base = (const char*)As + row * 128;
            int sw = (row & 7) << 4;
            af[0][mi] = *reinterpret_cast<const bf16x8*>(base + ((lb * 16) ^ sw));
            af[1][mi] = *reinterpret_cast<const bf16x8*>(base + ((64 + lb * 16) ^ sw));
        }
        for (int ni = 0; ni < 4; ++ni) {
            int row = wc * 64 + ni * 16 + la;
            const char* base = (const char*)Bs + row * 128;
            int sw = (row & 7) << 4;
            bfr[0][ni] = *reinterpret_cast<const bf16x8*>(base + ((lb * 16) ^ sw));
            bfr[1][ni] = *reinterpret_cast<const bf16x8*>(base + ((64 + lb * 16) ^ sw));
        }
        for (int kk = 0; kk < 2; ++kk)
            for (int mi = 0; mi < 4; ++mi)
                for (int ni = 0; ni < 4; ++ni)
                    acc[mi][ni] = __builtin_amdgcn_mfma_f32_16x16x32_bf16(
                        bfr[kk][ni], af[kk][mi], acc[mi][ni], 0, 0, 0);
    }

    for (int mi = 0; mi < 4; ++mi) {
        int n = bRow * 128 + wr * 64 + mi * 16 + la;
        for (int ni = 0; ni < 4; ++ni) {
            int colo0 = bCol * 128 + wc * 64 + ni * 16 + lb * 4;
            f32x4 bv4 = *reinterpret_cast<const f32x4*>(&bias[colo0]);
            f32x4 vv = acc[mi][ni] + bv4;
            __builtin_nontemporal_store(
                vv, reinterpret_cast<f32x4*>(&ofp[(size_t)n * 1024 + colo0]));
        }
    }
}

// ---------------- fused scores + softmax + PV ----------------
// grid 1024 (XCD-swizzled); block 256 = 4 waves x 16 q-rows; 32 chunks of 64 kv.
// KEY FIX (R12 counters): V is now STAGED IN LDS, so the PV step has NO
// global-load vmcnt consumers — FIFO vmcnt no longer forces in-chunk drains of
// the K/V prefetch or the NT-store queue. End-of-chunk vmcnt(4) retires
// mask+K+V stages, keeps the 4 NT stores in flight (1 chunk of ack slack).
// Pass 1: depth-2 prefetch via 4-slot ring (Ks[0],Ks[1],Vs[0],Vs[1]); its
// tail dummy stages park chunks 0,1 in Ks[0/1] = pass 2's K prologue.
// Store layout = R8's proven 64B/row pattern. No max-subtraction.
__global__ __launch_bounds__(256, 4) void attn_fused_k(
    const bf16_t* __restrict__ Qh, const bf16_t* __restrict__ Kh,
    const bf16_t* __restrict__ Vt, const unsigned int* __restrict__ mbits,
    float* __restrict__ P, bf16_t* __restrict__ attn)
{
    __shared__ bf16_t Ks[2][64 * 64];   // 2 x 8 KB K chunks
    __shared__ bf16_t Vs[2][64 * 64];   // 2 x 8 KB V chunks (pass1: K ring slots)
    __shared__ bf16_t Pb[4][16 * 64];   // 4 waves x 2 KB bf16 P chunk

    // XCD-bijective swizzle: 1024 = 8 XCDs x 128 -> each XCD owns 4 heads
    const int wg = blockIdx.x;
    const int swg = (wg & 7) * 128 + (wg >> 3);
    const int bh = swg >> 5, qs = swg & 31;

    const int tid = threadIdx.x, lane = tid & 63, wv = tid >> 6;  // 4 waves
    const int la = lane & 15, lg = lane >> 4;
    const int b_ = bh >> 4;
    const int qbase = qs * 64 + wv * 16;
    const int swz = (la & 7) << 4;

    bf16x8 qf0, qf1;
    {
        const bf16_t* qrow = Qh + ((size_t)bh * 2048 + qbase + la) * 64 + lg * 8;
        qf0 = *reinterpret_cast<const bf16x8*>(qrow);
        qf1 = *reinterpret_cast<const bf16x8*>(qrow + 32);
    }
    const char* Khb = (const char*)(Kh + ((size_t)bh << 17));
    const char* Vtb = (const char*)(Vt + ((size_t)bh << 17));
    const unsigned int* mrow = mbits + ((size_t)b_ * 2048 + qbase + la) * 64;
    const float SC = 0.125f * 1.4426950408889634f;

#define STAGE_KD(c, dst)                                                      \
    for (int i = 0; i < 2; ++i) {                                             \
        int o = i * 4096 + tid * 16;                                          \
        int row = o >> 7;                                                     \
        int cb = (o & 127) ^ ((row & 7) << 4);                                \
        load_lds16(Khb + (size_t)(c) * 8192 + row * 128 + cb, (char*)(dst) + o); \
    }
#define STAGE_V(c, bsel)                                                      \
    for (int i = 0; i < 2; ++i) {                                             \
        int o = i * 4096 + tid * 16;                                          \
        int row = o >> 7;                                                     \
        int cb = (o & 127) ^ ((row & 7) << 4);                                \
        load_lds16(Vtb + (size_t)row * 4096 + (size_t)(c) * 128 + cb,         \
                   (char*)Vs[bsel] + o);                                      \
    }

#define QK_TILE(ct, Kbase, acc)                                               \
    {                                                                         \
        int krow = (ct) * 16 + la;                                            \
        const char* kb = (Kbase) + krow * 128;                                \
        int sw = (krow & 7) << 4;                                             \
        bf16x8 kf0 = *reinterpret_cast<const bf16x8*>(kb + ((lg * 16) ^ sw)); \
        bf16x8 kf1 = *reinterpret_cast<const bf16x8*>(kb + ((64 + lg * 16) ^ sw)); \
        acc = __builtin_amdgcn_mfma_f32_16x16x32_bf16(kf0, qf0, acc, 0, 0, 0); \
        acc = __builtin_amdgcn_mfma_f32_16x16x32_bf16(kf1, qf1, acc, 0, 0, 0); \
    }

    // ---- pass 1: row sums of exp2(logit); 4-slot ring, depth-2 prefetch ----
    float ssum = 0.f;
    uint2 mws = *reinterpret_cast<const uint2*>(mrow);
    STAGE_KD(0, Ks[0])
    STAGE_KD(1, Ks[1])
    asm volatile("s_waitcnt vmcnt(2)" ::: "memory");  // K0 done; K1 in flight
    __builtin_amdgcn_s_barrier();
    for (int c = 0; c < 32; ++c) {
        uint2 mnext = *reinterpret_cast<const uint2*>(mrow + 2 * ((c + 1) & 31));
        {
            int cs = (c + 2) & 31;
            char* dst = ((c + 2) & 2) ? (char*)Vs[(c + 2) & 1] : (char*)Ks[(c + 2) & 1];
            STAGE_KD(cs, dst)
        }
        __builtin_amdgcn_sched_barrier(0);
        const char* Kbase = (c & 2) ? (const char*)Vs[c & 1] : (const char*)Ks[c & 1];
        unsigned mwarr[2] = {mws.x, mws.y};
        __builtin_amdgcn_s_setprio(1);
#pragma unroll
        for (int ct = 0; ct < 4; ++ct) {
            f32x4 acc = {};
            QK_TILE(ct, Kbase, acc)
            unsigned mw = mwarr[ct >> 1];
            int shift = ((ct & 1) << 4) + lg * 4;
            for (int r = 0; r < 4; ++r) {
                float t = __builtin_amdgcn_exp2f(acc[r] * SC);
                ssum += ((mw >> (shift + r)) & 1u) ? t : 0.f;
            }
        }
        __builtin_amdgcn_s_setprio(0);
        // retire K(c+1); keep mask(c+1) + K(c+2) in flight
        asm volatile("s_waitcnt vmcnt(3)" ::: "memory");
        __builtin_amdgcn_s_barrier();
        mws = mnext;
    }
    // drain tail stages (they parked chunks 0,1 into Ks[0],Ks[1] for pass 2)
    asm volatile("s_waitcnt vmcnt(0)" ::: "memory");
    // reduce over the 4 lg groups (each lane's q-row = la)
    ssum += __shfl_xor(ssum, 16, 64);
    ssum += __shfl_xor(ssum, 32, 64);
    // v_log_f32 IS log2 -> exp2(x*SC - log2(ssum)) = exp2(x*SC)/ssum
    const float nls = -__builtin_amdgcn_logf(ssum);

    // ---- pass 2: recompute, folded-norm exp2, NT P stores, LDS-V PV ----
    f32x4 accpv[4] = {};
    float* Pq = P + ((size_t)bh << 22) + (size_t)(qbase + la) * 2048;
    char* Pw = (char*)Pb[wv];
    mws = *reinterpret_cast<const uint2*>(mrow);
    STAGE_V(0, 0)
    asm volatile("s_waitcnt vmcnt(0)" ::: "memory");
    __builtin_amdgcn_s_barrier();
    for (int c = 0; c < 32; ++c) {
        int cn = (c + 1) & 31;
        uint2 mnext = *reinterpret_cast<const uint2*>(mrow + 2 * cn);
        STAGE_KD(cn, Ks[cn & 1])
        STAGE_V(cn, cn & 1)
        __builtin_amdgcn_sched_barrier(0);
        const char* Kbase = (const char*)Ks[c & 1];
        const char* Vbase = (const char*)Vs[c & 1];
        unsigned mwarr[2] = {mws.x, mws.y};
        f32x4 pvbuf[4];
        __builtin_amdgcn_s_setprio(1);
#pragma unroll
        for (int ct = 0; ct < 4; ++ct) {
            f32x4 acc = {};
            QK_TILE(ct, Kbase, acc)
            unsigned mw = mwarr[ct >> 1];
            int shift = ((ct & 1) << 4) + lg * 4;
            f32x4 pv;
            for (int r = 0; r < 4; ++r) {
                float t = __builtin_amdgcn_exp2f(__builtin_fmaf(acc[r], SC, nls));
                pv[r] = ((mw >> (shift + r)) & 1u) ? t : 0.f;
            }
            pvbuf[ct] = pv;
            bf16x4 pb4 = __builtin_convertvector(pv, bf16x4);
            *reinterpret_cast<bf16x4*>(Pw + ((la * 128 + ct * 32 + lg * 8) ^ swz)) = pb4;
        }
        // batched NT stores (R8 layout: 16 rows x contiguous 64B per instr)
#pragma unroll
        for (int ct = 0; ct < 4; ++ct)
            __builtin_nontemporal_store(
                pvbuf[ct], reinterpret_cast<f32x4*>(Pq + c * 64 + ct * 16 + lg * 4));
        // per-wave: Pb writes landed before A-fragment reads
        asm volatile("s_waitcnt lgkmcnt(0)" ::: "memory");
        __builtin_amdgcn_sched_barrier(0);
#pragma unroll
        for (int kbk = 0; kbk < 2; ++kbk) {
            bf16x8 pa = *reinterpret_cast<const bf16x8*>(
                Pw + ((la * 128 + kbk * 64 + lg * 16) ^ swz));
            for (int ni = 0; ni < 4; ++ni) {
                int vrow = ni * 16 + la;
                bf16x8 vf = *reinterpret_cast<const bf16x8*>(
                    Vbase + vrow * 128 + ((kbk * 64 + lg * 16) ^ ((vrow & 7) << 4)));
                accpv[ni] = __builtin_amdgcn_mfma_f32_16x16x32_bf16(pa, vf, accpv[ni], 0, 0, 0);
            }
        }
        __builtin_amdgcn_s_setprio(0);
        // retire mask+K+V stages; keep the 4 NT stores in flight
        asm volatile("s_waitcnt lgkmcnt(0) vmcnt(4)" ::: "memory");
        __builtin_amdgcn_s_barrier();
        mws = mnext;
    }
#undef STAGE_KD
#undef STAGE_V
#undef QK_TILE

    bf16_t* ab = attn + ((size_t)bh << 17);
    for (int ni = 0; ni < 4; ++ni)
        for (int r = 0; r < 4; ++r)
            ab[(size_t)(qbase + lg * 4 + r) * 64 + ni * 16 + la] = (bf16_t)accpv[ni][r];
}

extern "C" void kernel_launch(void* const* d_in, const int* in_sizes, int n_in,
                              void* d_out, int out_size, void* d_ws, size_t ws_size,
                              hipStream_t stream) {
    const float* q  = (const float*)d_in[0];
    const float* k  = (const float*)d_in[1];
    const float* v  = (const float*)d_in[2];
    const int* mask = (const int*)d_in[3];
    const float* Wq = (const float*)d_in[4];
    const float* bq = (const float*)d_in[5];
    const float* Wk = (const float*)d_in[6];
    const float* bk = (const float*)d_in[7];
    const float* Wv = (const float*)d_in[8];
    const float* bv = (const float*)d_in[9];
    const float* Wo = (const float*)d_in[10];
    const float* bo = (const float*)d_in[11];

    char* ws = (char*)d_ws;
    bf16_t* qb    = (bf16_t*)(ws + 0);
    bf16_t* kb    = (bf16_t*)(ws + 8388608);
    bf16_t* vb    = (bf16_t*)(ws + 16777216);
    bf16_t* wqb   = (bf16_t*)(ws + 25165824);
    bf16_t* wkb   = (bf16_t*)(ws + 27262976);
    bf16_t* wvb   = (bf16_t*)(ws + 29360128);
    bf16_t* wob   = (bf16_t*)(ws + 31457280);
    bf16_t* Qh    = (bf16_t*)(ws + 33554432);
    bf16_t* Kh    = (bf16_t*)(ws + 41943040);
    bf16_t* Vt    = (bf16_t*)(ws + 50331648);
    bf16_t* attnb = (bf16_t*)(ws + 58720256);
    unsigned long long* mbits = (unsigned long long*)(ws + 67108864);

    float* out   = (float*)d_out;
    float* score = out + 4194304;

    cvt_all_k<<<dim3(4096, 7), 256, 0, stream>>>(q, k, v, Wq, Wk, Wv, Wo,
                                                 qb, kb, vb, wqb, wkb, wvb, wob);
    pack_mask_k<<<32768, 256, 0, stream>>>(mask, mbits);

    gemm_qk<<<dim3(32, 8, 2), 256, 0, stream>>>(qb, kb, wqb, wkb, bq, bk, Qh, Kh);
    gemm_v<<<dim3(32, 8), 256, 0, stream>>>(vb, wvb, bv, Vt);

    attn_fused_k<<<1024, 256, 0, stream>>>(Qh, Kh, Vt, (const unsigned int*)mbits,
                                           score, attnb);

    gemm_out<<<dim3(32, 8), 256, 0, stream>>>(attnb, wob, bo, out);
}

// Round 14
// 239.089 us; speedup vs baseline: 1.8629x; 1.2508x over previous
//
#include <hip/hip_runtime.h>

typedef __bf16 bf16_t;
typedef __bf16 bf16x4 __attribute__((ext_vector_type(4)));
typedef __bf16 bf16x8 __attribute__((ext_vector_type(8)));
typedef float f32x4 __attribute__((ext_vector_type(4)));

__device__ __forceinline__ void load_lds16(const void* g, void* l) {
    __builtin_amdgcn_global_load_lds((const __attribute__((address_space(1))) void*)g,
                                     (__attribute__((address_space(3))) void*)l, 16, 0, 0);
}

// ---------------- fp32 -> bf16 converts (7 tensors, one launch) ----------------
__global__ void cvt_all_k(const float* __restrict__ q, const float* __restrict__ k,
                          const float* __restrict__ v, const float* __restrict__ wq,
                          const float* __restrict__ wk, const float* __restrict__ wv,
                          const float* __restrict__ wo,
                          bf16_t* __restrict__ oq, bf16_t* __restrict__ ok,
                          bf16_t* __restrict__ ov, bf16_t* __restrict__ owq,
                          bf16_t* __restrict__ owk, bf16_t* __restrict__ owv,
                          bf16_t* __restrict__ owo) {
    int y = blockIdx.y;
    int n = (y < 3) ? 4194304 : 1048576;
    int i = (blockIdx.x * 256 + threadIdx.x) * 4;
    if (i >= n) return;
    const float* s;
    bf16_t* d;
    switch (y) {
        case 0: s = q;  d = oq;  break;
        case 1: s = k;  d = ok;  break;
        case 2: s = v;  d = ov;  break;
        case 3: s = wq; d = owq; break;
        case 4: s = wk; d = owk; break;
        case 5: s = wv; d = owv; break;
        default: s = wo; d = owo; break;
    }
    f32x4 t = *reinterpret_cast<const f32x4*>(s + i);
    *reinterpret_cast<bf16x4*>(d + i) = __builtin_convertvector(t, bf16x4);
}

// ---------------- mask -> bitmask ----------------
__global__ void pack_mask_k(const int* __restrict__ mask, unsigned long long* __restrict__ bits) {
    int e = blockIdx.x * blockDim.x + threadIdx.x;
    unsigned long long b = __ballot(mask[e] != 0);
    if ((threadIdx.x & 63) == 0) bits[e >> 6] = b;
}

// ---------------- Q/K projection GEMM (swapped operands): C = A @ W^T + bias ----
__global__ __launch_bounds__(256, 3) void gemm_qk(
    const bf16_t* __restrict__ qb, const bf16_t* __restrict__ kb,
    const bf16_t* __restrict__ wq, const bf16_t* __restrict__ wk,
    const float* __restrict__ bq, const float* __restrict__ bk,
    bf16_t* __restrict__ Qh, bf16_t* __restrict__ Kh)
{
    const int z = blockIdx.z;
    const bf16_t* A = z ? kb : qb;
    const bf16_t* W = z ? wk : wq;
    const float* bias = z ? bk : bq;
    bf16_t* obf = z ? Kh : Qh;

    __shared__ bf16_t As[128 * 64];
    __shared__ bf16_t Bs[128 * 64];
    const int tid = threadIdx.x;
    const int lane = tid & 63;
    const int wv = tid >> 6;
    const int wr = wv >> 1, wc = wv & 1;
    const int la = lane & 15, lb = lane >> 4;
    const int bRow = blockIdx.x, bCol = blockIdx.y;
    f32x4 acc[4][4] = {};

    for (int k0 = 0; k0 < 1024; k0 += 64) {
        __syncthreads();
        for (int i = 0; i < 4; ++i) {
            int o = i * 4096 + tid * 16;
            int row = o >> 7;
            int cb = (o & 127) ^ ((row & 7) << 4);
            const char* sa = (const char*)A + (((size_t)(bRow * 128 + row)) * 1024 + k0) * 2 + cb;
            load_lds16(sa, (char*)As + i * 4096 + wv * 1024);
            const char* sb = (const char*)W + (((size_t)(bCol * 128 + row)) * 1024 + k0) * 2 + cb;
            load_lds16(sb, (char*)Bs + i * 4096 + wv * 1024);
        }
        __syncthreads();

        bf16x8 af[2][4], bfr[2][4];
        for (int mi = 0; mi < 4; ++mi) {
            int row = wr * 64 + mi * 16 + la;
            const char* base = (const char*)As + row * 128;
            int sw = (row & 7) << 4;
            af[0][mi] = *reinterpret_cast<const bf16x8*>(base + ((lb * 16) ^ sw));
            af[1][mi] = *reinterpret_cast<const bf16x8*>(base + ((64 + lb * 16) ^ sw));
        }
        for (int ni = 0; ni < 4; ++ni) {
            int row = wc * 64 + ni * 16 + la;
            const char* base = (const char*)Bs + row * 128;
            int sw = (row & 7) << 4;
            bfr[0][ni] = *reinterpret_cast<const bf16x8*>(base + ((lb * 16) ^ sw));
            bfr[1][ni] = *reinterpret_cast<const bf16x8*>(base + ((64 + lb * 16) ^ sw));
        }
        for (int kk = 0; kk < 2; ++kk)
            for (int mi = 0; mi < 4; ++mi)
                for (int ni = 0; ni < 4; ++ni)
                    acc[mi][ni] = __builtin_amdgcn_mfma_f32_16x16x32_bf16(
                        bfr[kk][ni], af[kk][mi], acc[mi][ni], 0, 0, 0);
    }

    for (int mi = 0; mi < 4; ++mi) {
        int n = bRow * 128 + wr * 64 + mi * 16 + la;
        int b_ = n >> 11, s_ = n & 2047;
        for (int ni = 0; ni < 4; ++ni) {
            int colo0 = bCol * 128 + wc * 64 + ni * 16 + lb * 4;
            f32x4 bv4 = *reinterpret_cast<const f32x4*>(&bias[colo0]);
            f32x4 vv = acc[mi][ni] + bv4;
            int h = colo0 >> 6, d0 = colo0 & 63;
            bf16x4 v4 = __builtin_convertvector(vv, bf16x4);
            *reinterpret_cast<bf16x4*>(
                &obf[(((size_t)(b_ * 16 + h) * 2048 + s_) << 6) + d0]) = v4;
        }
    }
}

// ---------------- V projection GEMM: V -> (b,h,dh,s) transposed ----------------
__global__ __launch_bounds__(256, 3) void gemm_v(
    const bf16_t* __restrict__ vb, const bf16_t* __restrict__ wv_,
    const float* __restrict__ bv, bf16_t* __restrict__ Vt)
{
    __shared__ bf16_t As[128 * 64];
    __shared__ bf16_t Bs[128 * 64];
    const int tid = threadIdx.x;
    const int lane = tid & 63;
    const int wv = tid >> 6;
    const int wr = wv >> 1, wc = wv & 1;
    const int la = lane & 15, lb = lane >> 4;
    const int bRow = blockIdx.x, bCol = blockIdx.y;
    f32x4 acc[4][4] = {};

    for (int k0 = 0; k0 < 1024; k0 += 64) {
        __syncthreads();
        for (int i = 0; i < 4; ++i) {
            int o = i * 4096 + tid * 16;
            int row = o >> 7;
            int cb = (o & 127) ^ ((row & 7) << 4);
            const char* sa = (const char*)vb + (((size_t)(bRow * 128 + row)) * 1024 + k0) * 2 + cb;
            load_lds16(sa, (char*)As + i * 4096 + wv * 1024);
            const char* sb = (const char*)wv_ + (((size_t)(bCol * 128 + row)) * 1024 + k0) * 2 + cb;
            load_lds16(sb, (char*)Bs + i * 4096 + wv * 1024);
        }
        __syncthreads();

        bf16x8 af[2][4], bfr[2][4];
        for (int mi = 0; mi < 4; ++mi) {
            int row = wr * 64 + mi * 16 + la;
            const char* base = (const char*)As + row * 128;
            int sw = (row & 7) << 4;
            af[0][mi] = *reinterpret_cast<const bf16x8*>(base + ((lb * 16) ^ sw));
            af[1][mi] = *reinterpret_cast<const bf16x8*>(base + ((64 + lb * 16) ^ sw));
        }
        for (int ni = 0; ni < 4; ++ni) {
            int row = wc * 64 + ni * 16 + la;
            const char* base = (const char*)Bs + row * 128;
            int sw = (row & 7) << 4;
            bfr[0][ni] = *reinterpret_cast<const bf16x8*>(base + ((lb * 16) ^ sw));
            bfr[1][ni] = *reinterpret_cast<const bf16x8*>(base + ((64 + lb * 16) ^ sw));
        }
        for (int kk = 0; kk < 2; ++kk)
            for (int mi = 0; mi < 4; ++mi)
                for (int ni = 0; ni < 4; ++ni)
                    acc[mi][ni] = __builtin_amdgcn_mfma_f32_16x16x32_bf16(
                        af[kk][mi], bfr[kk][ni], acc[mi][ni], 0, 0, 0);
    }

    for (int ni = 0; ni < 4; ++ni) {
        int colo = bCol * 128 + wc * 64 + ni * 16 + la;
        float bvv = bv[colo];
        int h = colo >> 6, d = colo & 63;
        for (int mi = 0; mi < 4; ++mi) {
            int n0 = bRow * 128 + wr * 64 + mi * 16 + lb * 4;
            int b_ = n0 >> 11, s0 = n0 & 2047;
            f32x4 vv = acc[mi][ni];
            vv[0] += bvv; vv[1] += bvv; vv[2] += bvv; vv[3] += bvv;
            bf16x4 v4 = __builtin_convertvector(vv, bf16x4);
            *reinterpret_cast<bf16x4*>(
                &Vt[((size_t)(b_ * 16 + h) * 64 + d) * 2048 + s0]) = v4;
        }
    }
}

// ---------------- output projection GEMM (swapped): out = attn @ Wo^T + bo ----
__global__ __launch_bounds__(256, 3) void gemm_out(
    const bf16_t* __restrict__ A, const bf16_t* __restrict__ W,
    const float* __restrict__ bias, float* __restrict__ ofp)
{
    __shared__ bf16_t As[128 * 64];
    __shared__ bf16_t Bs[128 * 64];
    const int tid = threadIdx.x;
    const int lane = tid & 63;
    const int wv = tid >> 6;
    const int wr = wv >> 1, wc = wv & 1;
    const int la = lane & 15, lb = lane >> 4;
    const int bRow = blockIdx.x, bCol = blockIdx.y;
    f32x4 acc[4][4] = {};

    for (int k0 = 0; k0 < 1024; k0 += 64) {
        __syncthreads();
        for (int i = 0; i < 4; ++i) {
            int o = i * 4096 + tid * 16;
            int row = o >> 7;
            int cb = (o & 127) ^ ((row & 7) << 4);
            const char* sa = (const char*)A + (((size_t)(bRow * 128 + row)) * 1024 + k0) * 2 + cb;
            load_lds16(sa, (char*)As + i * 4096 + wv * 1024);
            const char* sb = (const char*)W + (((size_t)(bCol * 128 + row)) * 1024 + k0) * 2 + cb;
            load_lds16(sb, (char*)Bs + i * 4096 + wv * 1024);
        }
        __syncthreads();

        bf16x8 af[2][4], bfr[2][4];
        for (int mi = 0; mi < 4; ++mi) {
            int row = wr * 64 + mi * 16 + la;
            const char* base = (const char*)As + row * 128;
            int sw = (row & 7) << 4;
            af[0][mi] = *reinterpret_cast<const bf16x8*>(base + ((lb * 16) ^ sw));
            af[1][mi] = *reinterpret_cast<const bf16x8*>(base + ((64 + lb * 16) ^ sw));
        }
        for (int ni = 0; ni < 4; ++ni) {
            int row = wc * 64 + ni * 16 + la;
            const char* base = (const char*)Bs + row * 128;
            int sw = (row & 7) << 4;
            bfr[0][ni] = *reinterpret_cast<const bf16x8*>(base + ((lb * 16) ^ sw));
            bfr[1][ni] = *reinterpret_cast<const bf16x8*>(base + ((64 + lb * 16) ^ sw));
        }
        for (int kk = 0; kk < 2; ++kk)
            for (int mi = 0; mi < 4; ++mi)
                for (int ni = 0; ni < 4; ++ni)
                    acc[mi][ni] = __builtin_amdgcn_mfma_f32_16x16x32_bf16(
                        bfr[kk][ni], af[kk][mi], acc[mi][ni], 0, 0, 0);
    }

    for (int mi = 0; mi < 4; ++mi) {
        int n = bRow * 128 + wr * 64 + mi * 16 + la;
        for (int ni = 0; ni < 4; ++ni) {
            int colo0 = bCol * 128 + wc * 64 + ni * 16 + lb * 4;
            f32x4 bv4 = *reinterpret_cast<const f32x4*>(&bias[colo0]);
            f32x4 vv = acc[mi][ni] + bv4;
            __builtin_nontemporal_store(
                vv, reinterpret_cast<f32x4*>(&ofp[(size_t)n * 1024 + colo0]));
        }
    }
}

// ---------------- fused scores + softmax + PV ----------------
// R13 structure (V staged in LDS, no in-loop vmcnt consumers) + FULL-LINE NT
// P stores: per 32-kv pair, ds_bpermute re-layouts lanes so each store instr
// covers 8 rows x one full 128B line (was 16 rows x 64B half-lines; R6 showed
// 1.4x write amplification). Target lane l pulls from source lane
// (l>>3)+16*(l&3) (+8 rows for the second instr), tile select l&4.
__global__ __launch_bounds__(256, 4) void attn_fused_k(
    const bf16_t* __restrict__ Qh, const bf16_t* __restrict__ Kh,
    const bf16_t* __restrict__ Vt, const unsigned int* __restrict__ mbits,
    float* __restrict__ P, bf16_t* __restrict__ attn)
{
    __shared__ bf16_t Ks[2][64 * 64];   // 2 x 8 KB K chunks
    __shared__ bf16_t Vs[2][64 * 64];   // 2 x 8 KB V chunks (pass1: K ring slots)
    __shared__ bf16_t Pb[4][16 * 64];   // 4 waves x 2 KB bf16 P chunk

    // XCD-bijective swizzle: 1024 = 8 XCDs x 128 -> each XCD owns 4 heads
    const int wg = blockIdx.x;
    const int swg = (wg & 7) * 128 + (wg >> 3);
    const int bh = swg >> 5, qs = swg & 31;

    const int tid = threadIdx.x, lane = tid & 63, wv = tid >> 6;  // 4 waves
    const int la = lane & 15, lg = lane >> 4;
    const int b_ = bh >> 4;
    const int qbase = qs * 64 + wv * 16;
    const int swz = (la & 7) << 4;

    bf16x8 qf0, qf1;
    {
        const bf16_t* qrow = Qh + ((size_t)bh * 2048 + qbase + la) * 64 + lg * 8;
        qf0 = *reinterpret_cast<const bf16x8*>(qrow);
        qf1 = *reinterpret_cast<const bf16x8*>(qrow + 32);
    }
    const char* Khb = (const char*)(Kh + ((size_t)bh << 17));
    const char* Vtb = (const char*)(Vt + ((size_t)bh << 17));
    const unsigned int* mrow = mbits + ((size_t)b_ * 2048 + qbase + la) * 64;
    const float SC = 0.125f * 1.4426950408889634f;

#define STAGE_KD(c, dst)                                                      \
    for (int i = 0; i < 2; ++i) {                                             \
        int o = i * 4096 + tid * 16;                                          \
        int row = o >> 7;                                                     \
        int cb = (o & 127) ^ ((row & 7) << 4);                                \
        load_lds16(Khb + (size_t)(c) * 8192 + row * 128 + cb, (char*)(dst) + o); \
    }
#define STAGE_V(c, bsel)                                                      \
    for (int i = 0; i < 2; ++i) {                                             \
        int o = i * 4096 + tid * 16;                                          \
        int row = o >> 7;                                                     \
        int cb = (o & 127) ^ ((row & 7) << 4);                                \
        load_lds16(Vtb + (size_t)row * 4096 + (size_t)(c) * 128 + cb,         \
                   (char*)Vs[bsel] + o);                                      \
    }

#define QK_TILE(ct, Kbase, acc)                                               \
    {                                                                         \
        int krow = (ct) * 16 + la;                                            \
        const char* kb = (Kbase) + krow * 128;                                \
        int sw = (krow & 7) << 4;                                             \
        bf16x8 kf0 = *reinterpret_cast<const bf16x8*>(kb + ((lg * 16) ^ sw)); \
        bf16x8 kf1 = *reinterpret_cast<const bf16x8*>(kb + ((64 + lg * 16) ^ sw)); \
        acc = __builtin_amdgcn_mfma_f32_16x16x32_bf16(kf0, qf0, acc, 0, 0, 0); \
        acc = __builtin_amdgcn_mfma_f32_16x16x32_bf16(kf1, qf1, acc, 0, 0, 0); \
    }

    // ---- pass 1: row sums of exp2(logit); 4-slot ring, depth-2 prefetch ----
    float ssum = 0.f;
    uint2 mws = *reinterpret_cast<const uint2*>(mrow);
    STAGE_KD(0, Ks[0])
    STAGE_KD(1, Ks[1])
    asm volatile("s_waitcnt vmcnt(2)" ::: "memory");  // K0 done; K1 in flight
    __builtin_amdgcn_s_barrier();
    for (int c = 0; c < 32; ++c) {
        uint2 mnext = *reinterpret_cast<const uint2*>(mrow + 2 * ((c + 1) & 31));
        {
            int cs = (c + 2) & 31;
            char* dst = ((c + 2) & 2) ? (char*)Vs[(c + 2) & 1] : (char*)Ks[(c + 2) & 1];
            STAGE_KD(cs, dst)
        }
        __builtin_amdgcn_sched_barrier(0);
        const char* Kbase = (c & 2) ? (const char*)Vs[c & 1] : (const char*)Ks[c & 1];
        unsigned mwarr[2] = {mws.x, mws.y};
        __builtin_amdgcn_s_setprio(1);
#pragma unroll
        for (int ct = 0; ct < 4; ++ct) {
            f32x4 acc = {};
            QK_TILE(ct, Kbase, acc)
            unsigned mw = mwarr[ct >> 1];
            int shift = ((ct & 1) << 4) + lg * 4;
            for (int r = 0; r < 4; ++r) {
                float t = __builtin_amdgcn_exp2f(acc[r] * SC);
                ssum += ((mw >> (shift + r)) & 1u) ? t : 0.f;
            }
        }
        __builtin_amdgcn_s_setprio(0);
        // retire K(c+1); keep mask(c+1) + K(c+2) in flight
        asm volatile("s_waitcnt vmcnt(3)" ::: "memory");
        __builtin_amdgcn_s_barrier();
        mws = mnext;
    }
    // drain tail stages (they parked chunks 0,1 into Ks[0],Ks[1] for pass 2)
    asm volatile("s_waitcnt vmcnt(0)" ::: "memory");
    // reduce over the 4 lg groups (each lane's q-row = la)
    ssum += __shfl_xor(ssum, 16, 64);
    ssum += __shfl_xor(ssum, 32, 64);
    // v_log_f32 IS log2 -> exp2(x*SC - log2(ssum)) = exp2(x*SC)/ssum
    const float nls = -__builtin_amdgcn_logf(ssum);

    // ---- pass 2: recompute, folded-norm exp2, FULL-LINE NT P stores, PV ----
    f32x4 accpv[4] = {};
    // full-line store base: row qbase + (lane>>3), col (lane&7)*4
    float* Pline = P + ((size_t)bh << 22) + (size_t)(qbase + (lane >> 3)) * 2048
                 + (lane & 7) * 4;
    const int bp0 = ((lane >> 3) + ((lane & 3) << 4)) << 2;  // src lane *4, instr j=0
    char* Pw = (char*)Pb[wv];
    mws = *reinterpret_cast<const uint2*>(mrow);
    STAGE_V(0, 0)
    asm volatile("s_waitcnt vmcnt(0)" ::: "memory");
    __builtin_amdgcn_s_barrier();
    for (int c = 0; c < 32; ++c) {
        int cn = (c + 1) & 31;
        uint2 mnext = *reinterpret_cast<const uint2*>(mrow + 2 * cn);
        STAGE_KD(cn, Ks[cn & 1])
        STAGE_V(cn, cn & 1)
        __builtin_amdgcn_sched_barrier(0);
        const char* Kbase = (const char*)Ks[c & 1];
        const char* Vbase = (const char*)Vs[c & 1];
        unsigned mwarr[2] = {mws.x, mws.y};
        f32x4 pvbuf[4];
        __builtin_amdgcn_s_setprio(1);
#pragma unroll
        for (int ct = 0; ct < 4; ++ct) {
            f32x4 acc = {};
            QK_TILE(ct, Kbase, acc)
            unsigned mw = mwarr[ct >> 1];
            int shift = ((ct & 1) << 4) + lg * 4;
            f32x4 pv;
            for (int r = 0; r < 4; ++r) {
                float t = __builtin_amdgcn_exp2f(__builtin_fmaf(acc[r], SC, nls));
                pv[r] = ((mw >> (shift + r)) & 1u) ? t : 0.f;
            }
            pvbuf[ct] = pv;
            bf16x4 pb4 = __builtin_convertvector(pv, bf16x4);
            *reinterpret_cast<bf16x4*>(Pw + ((la * 128 + ct * 32 + lg * 8) ^ swz)) = pb4;
        }
        // full-line NT stores: bpermute re-layout, 8 rows x 128B per instr
#pragma unroll
        for (int p = 0; p < 2; ++p) {
            f32x4 s0, s1;
#pragma unroll
            for (int d = 0; d < 4; ++d) {
                int Aw = __float_as_int(pvbuf[2 * p][d]);
                int Bw = __float_as_int(pvbuf[2 * p + 1][d]);
                int a0 = __builtin_amdgcn_ds_bpermute(bp0, Aw);
                int b0 = __builtin_amdgcn_ds_bpermute(bp0, Bw);
                int a1 = __builtin_amdgcn_ds_bpermute(bp0 + 32, Aw);
                int b1 = __builtin_amdgcn_ds_bpermute(bp0 + 32, Bw);
                s0[d] = __int_as_float((lane & 4) ? b0 : a0);
                s1[d] = __int_as_float((lane & 4) ? b1 : a1);
            }
            float* pb = Pline + c * 64 + p * 32;
            __builtin_nontemporal_store(s0, reinterpret_cast<f32x4*>(pb));
            __builtin_nontemporal_store(s1, reinterpret_cast<f32x4*>(pb + 8 * 2048));
        }
        // per-wave: Pb writes landed before A-fragment reads
        asm volatile("s_waitcnt lgkmcnt(0)" ::: "memory");
        __builtin_amdgcn_sched_barrier(0);
#pragma unroll
        for (int kbk = 0; kbk < 2; ++kbk) {
            bf16x8 pa = *reinterpret_cast<const bf16x8*>(
                Pw + ((la * 128 + kbk * 64 + lg * 16) ^ swz));
            for (int ni = 0; ni < 4; ++ni) {
                int vrow = ni * 16 + la;
                bf16x8 vf = *reinterpret_cast<const bf16x8*>(
                    Vbase + vrow * 128 + ((kbk * 64 + lg * 16) ^ ((vrow & 7) << 4)));
                accpv[ni] = __builtin_amdgcn_mfma_f32_16x16x32_bf16(pa, vf, accpv[ni], 0, 0, 0);
            }
        }
        __builtin_amdgcn_s_setprio(0);
        // retire mask+K+V stages; keep the 4 NT stores in flight
        asm volatile("s_waitcnt lgkmcnt(0) vmcnt(4)" ::: "memory");
        __builtin_amdgcn_s_barrier();
        mws = mnext;
    }
#undef STAGE_KD
#undef STAGE_V
#undef QK_TILE

    bf16_t* ab = attn + ((size_t)bh << 17);
    for (int ni = 0; ni < 4; ++ni)
        for (int r = 0; r < 4; ++r)
            ab[(size_t)(qbase + lg * 4 + r) * 64 + ni * 16 + la] = (bf16_t)accpv[ni][r];
}

extern "C" void kernel_launch(void* const* d_in, const int* in_sizes, int n_in,
                              void* d_out, int out_size, void* d_ws, size_t ws_size,
                              hipStream_t stream) {
    const float* q  = (const float*)d_in[0];
    const float* k  = (const float*)d_in[1];
    const float* v  = (const float*)d_in[2];
    const int* mask = (const int*)d_in[3];
    const float* Wq = (const float*)d_in[4];
    const float* bq = (const float*)d_in[5];
    const float* Wk = (const float*)d_in[6];
    const float* bk = (const float*)d_in[7];
    const float* Wv = (const float*)d_in[8];
    const float* bv = (const float*)d_in[9];
    const float* Wo = (const float*)d_in[10];
    const float* bo = (const float*)d_in[11];

    char* ws = (char*)d_ws;
    bf16_t* qb    = (bf16_t*)(ws + 0);
    bf16_t* kb    = (bf16_t*)(ws + 8388608);
    bf16_t* vb    = (bf16_t*)(ws + 16777216);
    bf16_t* wqb   = (bf16_t*)(ws + 25165824);
    bf16_t* wkb   = (bf16_t*)(ws + 27262976);
    bf16_t* wvb   = (bf16_t*)(ws + 29360128);
    bf16_t* wob   = (bf16_t*)(ws + 31457280);
    bf16_t* Qh    = (bf16_t*)(ws + 33554432);
    bf16_t* Kh    = (bf16_t*)(ws + 41943040);
    bf16_t* Vt    = (bf16_t*)(ws + 50331648);
    bf16_t* attnb = (bf16_t*)(ws + 58720256);
    unsigned long long* mbits = (unsigned long long*)(ws + 67108864);

    float* out   = (float*)d_out;
    float* score = out + 4194304;

    cvt_all_k<<<dim3(4096, 7), 256, 0, stream>>>(q, k, v, Wq, Wk, Wv, Wo,
                                                 qb, kb, vb, wqb, wkb, wvb, wob);
    pack_mask_k<<<32768, 256, 0, stream>>>(mask, mbits);

    gemm_qk<<<dim3(32, 8, 2), 256, 0, stream>>>(qb, kb, wqb, wkb, bq, bk, Qh, Kh);
    gemm_v<<<dim3(32, 8), 256, 0, stream>>>(vb, wvb, bv, Vt);

    attn_fused_k<<<1024, 256, 0, stream>>>(Qh, Kh, Vt, (const unsigned int*)mbits,
                                           score, attnb);

    gemm_out<<<dim3(32, 8), 256, 0, stream>>>(attnb, wob, bo, out);
}